// Round 7
// baseline (231.795 us; speedup 1.0000x reference)
//
#include <hip/hip_runtime.h>
#include <hip/hip_bf16.h>
#include <cmath>

typedef __bf16 bf16;
typedef __bf16 bf16x8 __attribute__((ext_vector_type(8)));
typedef __bf16 bf16x4 __attribute__((ext_vector_type(4)));
typedef float f32x4 __attribute__((ext_vector_type(4)));

#define QS 0.18033688f   // hd^-0.5 * log2(e), folded into Wq/bq

// async 16B global->LDS. LDS dest = wave-uniform base + lane*16.
__device__ __forceinline__ void load16_to_lds(const void* g, void* l) {
    __builtin_amdgcn_global_load_lds(
        (const __attribute__((address_space(1))) unsigned int*)g,
        (__attribute__((address_space(3))) unsigned int*)l, 16, 0, 0);
}

// ---------------------------------------------------------------------------
// f32 -> bf16 convert: [x(4M) | Wq(1M) | Wk(1M) | Wv(1M) | Wo(1M)] -> dst
// Wq segment is prescaled by QS (softmax scale folded into Q projection).
// ---------------------------------------------------------------------------
__global__ __launch_bounds__(256) void convert_kernel(
    const float* __restrict__ x,  const float* __restrict__ wq,
    const float* __restrict__ wk, const float* __restrict__ wv,
    const float* __restrict__ wo, bf16* __restrict__ dst)
{
    const size_t M1 = 1024ull * 1024ull, M4 = 4ull * M1;
    size_t i0 = ((size_t)blockIdx.x * 256 + threadIdx.x) * 8;
    const float* s;
    size_t off;
    float sc = 1.f;
    if      (i0 < M4)        { s = x;  off = i0; }
    else if (i0 < M4 + M1)   { s = wq; off = i0 - M4; sc = QS; }
    else if (i0 < M4 + 2*M1) { s = wk; off = i0 - M4 - M1; }
    else if (i0 < M4 + 3*M1) { s = wv; off = i0 - M4 - 2*M1; }
    else                     { s = wo; off = i0 - M4 - 3*M1; }
    float4 a = *(const float4*)(s + off);
    float4 b = *(const float4*)(s + off + 4);
    bf16x8 r = { (bf16)(a.x*sc), (bf16)(a.y*sc), (bf16)(a.z*sc), (bf16)(a.w*sc),
                 (bf16)(b.x*sc), (bf16)(b.y*sc), (bf16)(b.z*sc), (bf16)(b.w*sc) };
    *(bf16x8*)(dst + i0) = r;
}

// ---------------------------------------------------------------------------
// bf16 GEMM, m97 structure upgraded to BK=64: one barrier pair per 64 K-elems
// (halves the per-barrier drain stalls vs BK=32). 16B global_load_lds with
// XOR swizzle s = u ^ (row&7) on 8x16B-unit rows; af/bfr loaded per-kk to
// keep VGPR ~164 (3 waves/SIMD, LDS 32KB -> 3 blocks/CU unchanged).
// Output modes:
//  0 = bf16 plain [s][1024] (Q)                2 = V fragment-major (attn vf)
//  1 = K fragment-major (attn kf)              3 = f32 plain (oproj out)
// Fragment-major: elem (key,d of head bh, tile nt=key>>6) stored so that an
// attn wave's bf16x8 operand load is base + lane*16B (fully coalesced).
//   K: idx = ((bh*32+nt)*8 + (d>>5)*4 + (kt>>4))*512 + ((d>>3)&3)*128 + (kt&15)*8 + (d&7)
//   V: idx = ((bh*32+nt)*8 + (kt>>5)*4 + (d>>4))*512 + ((kt>>3)&3)*128 + (d&15)*8 + (kt&7)
// (kt = key&63)
// ---------------------------------------------------------------------------
template<int BM, int MODE>
__device__ __forceinline__ void gemm_core(
    const bf16* __restrict__ A, const bf16* __restrict__ W,
    const float* __restrict__ bias, void* __restrict__ C,
    int mb, int nb, float bias_scale)
{
    constexpr int IF = BM / 32;
    __shared__ __align__(16) bf16 As[BM * 64];
    __shared__ __align__(16) bf16 Bs[128 * 64];

    const int tid  = threadIdx.x;
    const int lane = tid & 63;
    const int wave = tid >> 6;
    const int wr   = (wave >> 1) * (BM / 2);
    const int wc   = (wave & 1) * 64;
    const int l15  = lane & 15;
    const int l4   = lane >> 4;
    const int sw   = l15 & 7;                 // row&7 for swizzled read

    f32x4 acc[IF][4] = {};

    for (int kt = 0; kt < 16; ++kt) {
#pragma unroll
        for (int it = 0; it < BM / 32; ++it) {        // A: BM rows x 8 units
            int c = it * 256 + tid;
            int scol = ((c & 7) ^ ((c >> 3) & 7)) * 8;
            load16_to_lds(&A[(size_t)(mb * BM + (c >> 3)) * 1024 + kt * 64 + scol],
                          &As[(it * 256 + (tid & 192)) * 8]);
        }
#pragma unroll
        for (int it = 0; it < 4; ++it) {              // B: 128 rows x 8 units
            int c = it * 256 + tid;
            int scol = ((c & 7) ^ ((c >> 3) & 7)) * 8;
            load16_to_lds(&W[(size_t)(nb * 128 + (c >> 3)) * 1024 + kt * 64 + scol],
                          &Bs[(it * 256 + (tid & 192)) * 8]);
        }
        __syncthreads();
#pragma unroll
        for (int kk = 0; kk < 2; ++kk) {
            bf16x8 af[IF], bfr[4];
#pragma unroll
            for (int i = 0; i < IF; ++i)
                af[i] = *(const bf16x8*)&As[(wr + i * 16 + l15) * 64
                            + (((kk * 4 + l4) ^ sw) * 8)];
#pragma unroll
            for (int j = 0; j < 4; ++j)
                bfr[j] = *(const bf16x8*)&Bs[(wc + j * 16 + l15) * 64
                            + (((kk * 4 + l4) ^ sw) * 8)];
#pragma unroll
            for (int i = 0; i < IF; ++i)
#pragma unroll
                for (int j = 0; j < 4; ++j)
                    acc[i][j] = __builtin_amdgcn_mfma_f32_16x16x32_bf16(
                        af[i], bfr[j], acc[i][j], 0, 0, 0);
        }
        __syncthreads();
    }

    if (MODE == 1 || MODE == 2) {
#pragma unroll
        for (int j = 0; j < 4; ++j) {
            int D = nb * 128 + wc + j * 16 + l15;
            float bv = bias ? bias[D] : 0.f;
            int hh = D >> 6, d = D & 63;
#pragma unroll
            for (int i = 0; i < IF; ++i) {
                int S0 = mb * BM + wr + i * 16 + l4 * 4;
#pragma unroll
                for (int r = 0; r < 4; ++r) {
                    int S = S0 + r;
                    int bb = S >> 11, key = S & 2047;
                    int bh = bb * 16 + hh, nt = key >> 6, ktl = key & 63;
                    size_t idx;
                    if (MODE == 1)
                        idx = ((size_t)(bh * 32 + nt) * 8 + (d >> 5) * 4 + (ktl >> 4)) * 512
                            + ((d >> 3) & 3) * 128 + (ktl & 15) * 8 + (d & 7);
                    else
                        idx = ((size_t)(bh * 32 + nt) * 8 + (ktl >> 5) * 4 + (d >> 4)) * 512
                            + ((ktl >> 3) & 3) * 128 + (d & 15) * 8 + (ktl & 7);
                    ((bf16*)C)[idx] = (bf16)(acc[i][j][r] + bv);
                }
            }
        }
    } else {
#pragma unroll
        for (int j = 0; j < 4; ++j) {
            int col = nb * 128 + wc + j * 16 + l15;
            float bv = bias ? bias[col] * bias_scale : 0.f;
#pragma unroll
            for (int i = 0; i < IF; ++i) {
                int row0 = mb * BM + wr + i * 16 + l4 * 4;
#pragma unroll
                for (int r = 0; r < 4; ++r) {
                    float val = acc[i][j][r] + bv;
                    size_t idx = (size_t)(row0 + r) * 1024 + col;
                    if (MODE == 3) ((float*)C)[idx] = val;
                    else           ((bf16*)C)[idx]  = (bf16)val;
                }
            }
        }
    }
}

__global__ __launch_bounds__(256) void qkv_kernel(
    const bf16* __restrict__ xb,
    const bf16* __restrict__ wqb, const float* __restrict__ bq,
    const bf16* __restrict__ wkb,
    const bf16* __restrict__ wvb, const float* __restrict__ bv,
    bf16* __restrict__ q, bf16* __restrict__ kfb, bf16* __restrict__ vfb)
{
    int mb = blockIdx.x;
    int nbg = blockIdx.y;
    int sel = nbg >> 3, nb = nbg & 7;
    if      (sel == 0) gemm_core<128, 0>(xb, wqb, bq,      q,   mb, nb, QS);
    else if (sel == 1) gemm_core<128, 1>(xb, wkb, nullptr, kfb, mb, nb, 1.f);
    else               gemm_core<128, 2>(xb, wvb, bv,      vfb, mb, nb, 1.f);
}

__global__ __launch_bounds__(256) void oproj_kernel(
    const bf16* __restrict__ ao, const bf16* __restrict__ wob,
    const float* __restrict__ bo, float* __restrict__ out)
{
    gemm_core<128, 3>(ao, wob, bo, out, blockIdx.x, blockIdx.y, 1.f);
}

// ---------------------------------------------------------------------------
// Flash attention v8: v7's 64-row waves + 4 independent waves PER WORKGROUP.
// v5/v6/v7 occupancy never exceeded ~24% despite tiny VGPR/LDS and thousands
// of blocks -> resident-wave count appears capped by concurrent WORKGROUPS
// per CU, so 1-wave workgroups waste wave slots. Packaging 4 free-running
// waves (no barriers, per-wave Ps) per 256-thread block raises waves/CU
// ~2-3x at the same workgroup count. The 80 valid (wt,chunk) units per bh
// are densely enumerated (no instant-exit waves), heavy-first, 4 per block:
// grid (32 bh, 20). K/V fragments time-share one register block (load K,
// QK+softmax, load V into same regs, PV) to keep VGPR ~<=170 for 3 waves/SIMD
// (launch_bounds(256,3)).
// Fixed-max softmax (p = 2^s); split-K chunks of 8 tiles; combine_kernel
// normalizes rows >= 512. K/V direct from L2, fragment-major.
// ---------------------------------------------------------------------------
__global__ __launch_bounds__(256, 3) void attn_kernel(
    const bf16* __restrict__ q, const bf16* __restrict__ kfb,
    const bf16* __restrict__ vfb, bf16* __restrict__ o,
    float* __restrict__ pbuf)
{
    __shared__ __align__(16) bf16 Ps[4][64 * 72];   // per-wave [q][key], stride 72

    const int tid  = threadIdx.x;
    const int lane = tid & 63;
    const int wave = tid >> 6;
    const int l15  = lane & 15;
    const int l4   = lane >> 4;

    const int bh = blockIdx.x;                // fast dim -> XCD = bh % 8
    const int b  = bh >> 4, h = bh & 15;

    // dense (wt, chunk) enumeration, heavy-first; i = 0..79
    const int i = blockIdx.y * 4 + wave;
    int wt, chunk;
    if (i < 32)      { wt = 31 - (i >> 2);          chunk = i & 3; }
    else if (i < 56) { int j = i - 32; wt = 23 - j / 3;   chunk = j % 3; }
    else if (i < 72) { int j = i - 56; wt = 15 - (j >> 1); chunk = j & 1; }
    else             { wt = 7 - (i - 72);           chunk = 0; }

    const int qrow0 = wt * 64;                // wave's first q row
    const int n   = wt + 1;                   // key tiles for this q-tile
    const int nch = (wt + 8) >> 3;            // chunks of 8
    const int nt0 = chunk * 8;
    const int nt1 = (nt0 + 8 < n) ? (nt0 + 8) : n;

    bf16x8 qf[4][2];
#pragma unroll
    for (int qb = 0; qb < 4; ++qb)
#pragma unroll
        for (int kk = 0; kk < 2; ++kk)
            qf[qb][kk] = *(const bf16x8*)&q[(size_t)(b * 2048 + qrow0 + qb * 16 + l15) * 1024
                                           + h * 64 + kk * 32 + l4 * 8];

    const bf16* kb = kfb + (size_t)bh * 131072;   // 32 tiles * 4096 elems
    const bf16* vb = vfb + (size_t)bh * 131072;

    f32x4 oacc[4][4] = {};
    float lsum[4] = { 0.f, 0.f, 0.f, 0.f };

    for (int nt = nt0; nt < nt1; ++nt) {
        const bf16* kt_ = kb + nt * 4096;
        const bf16* vt_ = vb + nt * 4096;

        // K fragments -> fr (time-shared register block)
        bf16x8 fr[2][4];
#pragma unroll
        for (int kk = 0; kk < 2; ++kk)
#pragma unroll
            for (int j = 0; j < 4; ++j)
                fr[kk][j] = *(const bf16x8*)&kt_[(kk * 4 + j) * 512 + lane * 8];

        const bool diag = (nt == n - 1);
#pragma unroll
        for (int qb = 0; qb < 4; ++qb) {
            // St[key][q] = K . Q^T for this q-fragment
            f32x4 s[4] = {};
#pragma unroll
            for (int kk = 0; kk < 2; ++kk)
#pragma unroll
                for (int j = 0; j < 4; ++j)
                    s[j] = __builtin_amdgcn_mfma_f32_16x16x32_bf16(
                        fr[kk][j], qf[qb][kk], s[j], 0, 0, 0);

            // fixed-max: p = 2^s; mask only on the diagonal tile; fused cvt
            if (diag) {
                int qg = qrow0 + qb * 16 + l15;
#pragma unroll
                for (int j = 0; j < 4; ++j) {
                    int kg0 = nt * 64 + j * 16 + l4 * 4;
                    float e0 = (kg0 + 0 > qg) ? 0.f : __builtin_amdgcn_exp2f(s[j][0]);
                    float e1 = (kg0 + 1 > qg) ? 0.f : __builtin_amdgcn_exp2f(s[j][1]);
                    float e2 = (kg0 + 2 > qg) ? 0.f : __builtin_amdgcn_exp2f(s[j][2]);
                    float e3 = (kg0 + 3 > qg) ? 0.f : __builtin_amdgcn_exp2f(s[j][3]);
                    lsum[qb] += (e0 + e1) + (e2 + e3);
                    bf16x4 pk = { (bf16)e0, (bf16)e1, (bf16)e2, (bf16)e3 };
                    *(bf16x4*)&Ps[wave][(qb * 16 + l15) * 72 + j * 16 + l4 * 4] = pk;
                }
            } else {
#pragma unroll
                for (int j = 0; j < 4; ++j) {
                    float e0 = __builtin_amdgcn_exp2f(s[j][0]);
                    float e1 = __builtin_amdgcn_exp2f(s[j][1]);
                    float e2 = __builtin_amdgcn_exp2f(s[j][2]);
                    float e3 = __builtin_amdgcn_exp2f(s[j][3]);
                    lsum[qb] += (e0 + e1) + (e2 + e3);
                    bf16x4 pk = { (bf16)e0, (bf16)e1, (bf16)e2, (bf16)e3 };
                    *(bf16x4*)&Ps[wave][(qb * 16 + l15) * 72 + j * 16 + l4 * 4] = pk;
                }
            }
        }

        // V fragments reuse fr
#pragma unroll
        for (int kk = 0; kk < 2; ++kk)
#pragma unroll
            for (int j = 0; j < 4; ++j)
                fr[kk][j] = *(const bf16x8*)&vt_[(kk * 4 + j) * 512 + lane * 8];

        // O += P . V, four P-fragments per V-fragment register
#pragma unroll
        for (int kk = 0; kk < 2; ++kk) {
            bf16x8 pf[4];
#pragma unroll
            for (int qb = 0; qb < 4; ++qb)
                pf[qb] = *(const bf16x8*)&Ps[wave][(qb * 16 + l15) * 72 + kk * 32 + l4 * 8];
#pragma unroll
            for (int f = 0; f < 4; ++f)
#pragma unroll
                for (int qb = 0; qb < 4; ++qb)
                    oacc[qb][f] = __builtin_amdgcn_mfma_f32_16x16x32_bf16(
                        pf[qb], fr[kk][f], oacc[qb][f], 0, 0, 0);
        }
    }

    if (nch == 1) {
        // single chunk: normalize and store directly
#pragma unroll
        for (int qb = 0; qb < 4; ++qb) {
            float ls = lsum[qb];
            ls += __shfl_xor(ls, 16, 64);
            ls += __shfl_xor(ls, 32, 64);
            float rinv[4];
#pragma unroll
            for (int r = 0; r < 4; ++r) rinv[r] = 1.f / __shfl(ls, l4 * 4 + r, 64);
#pragma unroll
            for (int f = 0; f < 4; ++f)
#pragma unroll
                for (int r = 0; r < 4; ++r)
                    o[(size_t)(b * 2048 + qrow0 + qb * 16 + l4 * 4 + r) * 1024 + h * 64 + f * 16 + l15]
                        = (bf16)(oacc[qb][f][r] * rinv[r]);
        }
    } else {
        // partial: unnormalized O (f32, [q][d]) + per-row l at [4096..4160)
        float* ps = pbuf + ((size_t)(bh * 32 + wt) * 4 + chunk) * 4160;
#pragma unroll
        for (int qb = 0; qb < 4; ++qb) {
            float ls = lsum[qb];
            ls += __shfl_xor(ls, 16, 64);
            ls += __shfl_xor(ls, 32, 64);
            if (l4 == 0) ps[4096 + qb * 16 + l15] = ls;
#pragma unroll
            for (int f = 0; f < 4; ++f)
#pragma unroll
                for (int r = 0; r < 4; ++r)
                    ps[(qb * 16 + l4 * 4 + r) * 64 + f * 16 + l15] = oacc[qb][f][r];
        }
    }
}

// ---------------------------------------------------------------------------
// Sum <=4 partial chunks, normalize, store bf16 to ao. One block per
// (bh, wt >= 8); 256 threads: thread t owns q = t>>2, d = (t&3)*16 .. +16.
// ---------------------------------------------------------------------------
__global__ __launch_bounds__(256) void combine_kernel(
    const float* __restrict__ pbuf, bf16* __restrict__ ao)
{
    const int bh = blockIdx.x;
    const int wt = 8 + blockIdx.y;
    const int b = bh >> 4, h = bh & 15;
    const int n   = wt + 1;
    const int nch = (n + 7) >> 3;

    const int tid = threadIdx.x;
    const int qq  = tid >> 2;
    const int d0  = (tid & 3) * 16;

    const float* base0 = pbuf + (size_t)(bh * 32 + wt) * 4 * 4160;

    float ls = 0.f;
    float acc[16] = {};
    for (int c = 0; c < nch; ++c) {
        const float* p = base0 + c * 4160;
        ls += p[4096 + qq];
#pragma unroll
        for (int g = 0; g < 4; ++g) {
            float4 a = *(const float4*)(p + qq * 64 + d0 + g * 4);
            acc[g*4+0] += a.x; acc[g*4+1] += a.y; acc[g*4+2] += a.z; acc[g*4+3] += a.w;
        }
    }
    float inv = 1.f / ls;
    bf16* dst = &ao[(size_t)(b * 2048 + wt * 64 + qq) * 1024 + h * 64 + d0];
    bf16x8 r0 = { (bf16)(acc[0]*inv), (bf16)(acc[1]*inv), (bf16)(acc[2]*inv), (bf16)(acc[3]*inv),
                  (bf16)(acc[4]*inv), (bf16)(acc[5]*inv), (bf16)(acc[6]*inv), (bf16)(acc[7]*inv) };
    bf16x8 r1 = { (bf16)(acc[8]*inv), (bf16)(acc[9]*inv), (bf16)(acc[10]*inv), (bf16)(acc[11]*inv),
                  (bf16)(acc[12]*inv), (bf16)(acc[13]*inv), (bf16)(acc[14]*inv), (bf16)(acc[15]*inv) };
    *(bf16x8*)dst = r0;
    *(bf16x8*)(dst + 8) = r1;
}

// ---------------------------------------------------------------------------
extern "C" void kernel_launch(void* const* d_in, const int* in_sizes, int n_in,
                              void* d_out, int out_size, void* d_ws, size_t ws_size,
                              hipStream_t stream)
{
    const float* x  = (const float*)d_in[0];
    // d_in[1] = causal mask, implemented in-kernel
    const float* Wq = (const float*)d_in[2];
    const float* bq = (const float*)d_in[3];
    const float* Wk = (const float*)d_in[4];
    const float* Wv = (const float*)d_in[5];
    const float* bv = (const float*)d_in[6];
    const float* Wo = (const float*)d_in[7];
    const float* bo = (const float*)d_in[8];
    float* out = (float*)d_out;

    const size_t M1 = 1024ull * 1024ull, M4 = 4ull * M1;
    bf16* base = (bf16*)d_ws;
    bf16* xb  = base;              // 4M; dead after qkv -> ao aliases it
    bf16* wqb = base + M4;
    bf16* wkb = base + M4 + M1;
    bf16* wvb = base + M4 + 2 * M1;
    bf16* wob = base + M4 + 3 * M1;
    bf16* q   = base + 8 * M1;
    bf16* kfb = base + 12 * M1;    // K fragment-major
    bf16* vfb = base + 16 * M1;    // V fragment-major
    bf16* ao  = xb;
    float* pbuf = (float*)(base + 20 * M1);   // 1024 tiles * 4 chunks * 4160 f32 = 68 MB

    convert_kernel<<<4096, 256, 0, stream>>>(x, Wq, Wk, Wv, Wo, base);
    qkv_kernel<<<dim3(32, 24), 256, 0, stream>>>(xb, wqb, bq, wkb, wvb, bv, q, kfb, vfb);
    attn_kernel<<<dim3(32, 20), 256, 0, stream>>>(q, kfb, vfb, ao, pbuf);
    combine_kernel<<<dim3(32, 24), 256, 0, stream>>>(pbuf, ao);
    oproj_kernel<<<dim3(32, 8), 256, 0, stream>>>(ao, wob, bo, out);
}

// Round 8
// 216.788 us; speedup vs baseline: 1.0692x; 1.0692x over previous
//
#include <hip/hip_runtime.h>
#include <hip/hip_bf16.h>
#include <cmath>

typedef __bf16 bf16;
typedef __bf16 bf16x8 __attribute__((ext_vector_type(8)));
typedef __bf16 bf16x4 __attribute__((ext_vector_type(4)));
typedef float f32x4 __attribute__((ext_vector_type(4)));

#define QS 0.18033688f   // hd^-0.5 * log2(e), folded into Wq/bq

// async 16B global->LDS. LDS dest = wave-uniform base + lane*16.
__device__ __forceinline__ void load16_to_lds(const void* g, void* l) {
    __builtin_amdgcn_global_load_lds(
        (const __attribute__((address_space(1))) unsigned int*)g,
        (__attribute__((address_space(3))) unsigned int*)l, 16, 0, 0);
}

// ---------------------------------------------------------------------------
// f32 -> bf16 convert: [x(4M) | Wq(1M) | Wk(1M) | Wv(1M) | Wo(1M)] -> dst
// Wq segment is prescaled by QS (softmax scale folded into Q projection).
// ---------------------------------------------------------------------------
__global__ __launch_bounds__(256) void convert_kernel(
    const float* __restrict__ x,  const float* __restrict__ wq,
    const float* __restrict__ wk, const float* __restrict__ wv,
    const float* __restrict__ wo, bf16* __restrict__ dst)
{
    const size_t M1 = 1024ull * 1024ull, M4 = 4ull * M1;
    size_t i0 = ((size_t)blockIdx.x * 256 + threadIdx.x) * 8;
    const float* s;
    size_t off;
    float sc = 1.f;
    if      (i0 < M4)        { s = x;  off = i0; }
    else if (i0 < M4 + M1)   { s = wq; off = i0 - M4; sc = QS; }
    else if (i0 < M4 + 2*M1) { s = wk; off = i0 - M4 - M1; }
    else if (i0 < M4 + 3*M1) { s = wv; off = i0 - M4 - 2*M1; }
    else                     { s = wo; off = i0 - M4 - 3*M1; }
    float4 a = *(const float4*)(s + off);
    float4 b = *(const float4*)(s + off + 4);
    bf16x8 r = { (bf16)(a.x*sc), (bf16)(a.y*sc), (bf16)(a.z*sc), (bf16)(a.w*sc),
                 (bf16)(b.x*sc), (bf16)(b.y*sc), (bf16)(b.z*sc), (bf16)(b.w*sc) };
    *(bf16x8*)(dst + i0) = r;
}

// ---------------------------------------------------------------------------
// bf16 GEMM, m97 structure with BK=64: one barrier pair per 64 K-elems.
// LDS tiles are passed in from the KERNEL (declared once at kernel scope):
// v8 bug: static __shared__ inside this inlined function got a SEPARATE
// 32 KB allocation per MODE branch (3x = 96 KB -> 1 block/CU -> 83.8us qkv).
// Output modes:
//  0 = bf16 plain [s][1024] (Q)                2 = V fragment-major (attn vf)
//  1 = K fragment-major (attn kf)              3 = f32 plain (oproj out)
// Fragment-major: elem (key,d of head bh, tile nt=key>>6) stored so that an
// attn wave's bf16x8 operand load is base + lane*16B (fully coalesced).
//   K: idx = ((bh*32+nt)*8 + (d>>5)*4 + (kt>>4))*512 + ((d>>3)&3)*128 + (kt&15)*8 + (d&7)
//   V: idx = ((bh*32+nt)*8 + (kt>>5)*4 + (d>>4))*512 + ((kt>>3)&3)*128 + (d&15)*8 + (kt&7)
// (kt = key&63)
// ---------------------------------------------------------------------------
template<int BM, int MODE>
__device__ __forceinline__ void gemm_core(
    bf16* __restrict__ As, bf16* __restrict__ Bs,
    const bf16* __restrict__ A, const bf16* __restrict__ W,
    const float* __restrict__ bias, void* __restrict__ C,
    int mb, int nb, float bias_scale)
{
    constexpr int IF = BM / 32;

    const int tid  = threadIdx.x;
    const int lane = tid & 63;
    const int wave = tid >> 6;
    const int wr   = (wave >> 1) * (BM / 2);
    const int wc   = (wave & 1) * 64;
    const int l15  = lane & 15;
    const int l4   = lane >> 4;
    const int sw   = l15 & 7;                 // row&7 for swizzled read

    f32x4 acc[IF][4] = {};

    for (int kt = 0; kt < 16; ++kt) {
#pragma unroll
        for (int it = 0; it < BM / 32; ++it) {        // A: BM rows x 8 units
            int c = it * 256 + tid;
            int scol = ((c & 7) ^ ((c >> 3) & 7)) * 8;
            load16_to_lds(&A[(size_t)(mb * BM + (c >> 3)) * 1024 + kt * 64 + scol],
                          &As[(it * 256 + (tid & 192)) * 8]);
        }
#pragma unroll
        for (int it = 0; it < 4; ++it) {              // B: 128 rows x 8 units
            int c = it * 256 + tid;
            int scol = ((c & 7) ^ ((c >> 3) & 7)) * 8;
            load16_to_lds(&W[(size_t)(nb * 128 + (c >> 3)) * 1024 + kt * 64 + scol],
                          &Bs[(it * 256 + (tid & 192)) * 8]);
        }
        __syncthreads();
#pragma unroll
        for (int kk = 0; kk < 2; ++kk) {
            bf16x8 af[IF], bfr[4];
#pragma unroll
            for (int i = 0; i < IF; ++i)
                af[i] = *(const bf16x8*)&As[(wr + i * 16 + l15) * 64
                            + (((kk * 4 + l4) ^ sw) * 8)];
#pragma unroll
            for (int j = 0; j < 4; ++j)
                bfr[j] = *(const bf16x8*)&Bs[(wc + j * 16 + l15) * 64
                            + (((kk * 4 + l4) ^ sw) * 8)];
#pragma unroll
            for (int i = 0; i < IF; ++i)
#pragma unroll
                for (int j = 0; j < 4; ++j)
                    acc[i][j] = __builtin_amdgcn_mfma_f32_16x16x32_bf16(
                        af[i], bfr[j], acc[i][j], 0, 0, 0);
        }
        __syncthreads();
    }

    if (MODE == 1 || MODE == 2) {
#pragma unroll
        for (int j = 0; j < 4; ++j) {
            int D = nb * 128 + wc + j * 16 + l15;
            float bv = bias ? bias[D] : 0.f;
            int hh = D >> 6, d = D & 63;
#pragma unroll
            for (int i = 0; i < IF; ++i) {
                int S0 = mb * BM + wr + i * 16 + l4 * 4;
#pragma unroll
                for (int r = 0; r < 4; ++r) {
                    int S = S0 + r;
                    int bb = S >> 11, key = S & 2047;
                    int bh = bb * 16 + hh, nt = key >> 6, ktl = key & 63;
                    size_t idx;
                    if (MODE == 1)
                        idx = ((size_t)(bh * 32 + nt) * 8 + (d >> 5) * 4 + (ktl >> 4)) * 512
                            + ((d >> 3) & 3) * 128 + (ktl & 15) * 8 + (d & 7);
                    else
                        idx = ((size_t)(bh * 32 + nt) * 8 + (ktl >> 5) * 4 + (d >> 4)) * 512
                            + ((ktl >> 3) & 3) * 128 + (d & 15) * 8 + (ktl & 7);
                    ((bf16*)C)[idx] = (bf16)(acc[i][j][r] + bv);
                }
            }
        }
    } else {
#pragma unroll
        for (int j = 0; j < 4; ++j) {
            int col = nb * 128 + wc + j * 16 + l15;
            float bv = bias ? bias[col] * bias_scale : 0.f;
#pragma unroll
            for (int i = 0; i < IF; ++i) {
                int row0 = mb * BM + wr + i * 16 + l4 * 4;
#pragma unroll
                for (int r = 0; r < 4; ++r) {
                    float val = acc[i][j][r] + bv;
                    size_t idx = (size_t)(row0 + r) * 1024 + col;
                    if (MODE == 3) ((float*)C)[idx] = val;
                    else           ((bf16*)C)[idx]  = (bf16)val;
                }
            }
        }
    }
}

__global__ __launch_bounds__(256) void qkv_kernel(
    const bf16* __restrict__ xb,
    const bf16* __restrict__ wqb, const float* __restrict__ bq,
    const bf16* __restrict__ wkb,
    const bf16* __restrict__ wvb, const float* __restrict__ bv,
    bf16* __restrict__ q, bf16* __restrict__ kfb, bf16* __restrict__ vfb)
{
    __shared__ __align__(16) bf16 As[128 * 64];   // single allocation,
    __shared__ __align__(16) bf16 Bs[128 * 64];   // shared by all 3 branches
    int mb = blockIdx.x;
    int nbg = blockIdx.y;
    int sel = nbg >> 3, nb = nbg & 7;
    if      (sel == 0) gemm_core<128, 0>(As, Bs, xb, wqb, bq,      q,   mb, nb, QS);
    else if (sel == 1) gemm_core<128, 1>(As, Bs, xb, wkb, nullptr, kfb, mb, nb, 1.f);
    else               gemm_core<128, 2>(As, Bs, xb, wvb, bv,      vfb, mb, nb, 1.f);
}

__global__ __launch_bounds__(256) void oproj_kernel(
    const bf16* __restrict__ ao, const bf16* __restrict__ wob,
    const float* __restrict__ bo, float* __restrict__ out)
{
    __shared__ __align__(16) bf16 As[128 * 64];
    __shared__ __align__(16) bf16 Bs[128 * 64];
    gemm_core<128, 3>(As, Bs, ao, wob, bo, out, blockIdx.x, blockIdx.y, 1.f);
}

// ---------------------------------------------------------------------------
// Flash attention v8 (unchanged from R7): 64-row waves, 4 independent waves
// per 256-thread workgroup (no barriers, per-wave Ps), dense heavy-first
// (wt,chunk) enumeration, K/V fragments time-share one register block,
// split-K chunks of 8 tiles, fixed-max softmax (p = 2^s), K/V direct from
// L2 in fragment-major layout. combine_kernel normalizes rows >= 512.
// ---------------------------------------------------------------------------
__global__ __launch_bounds__(256, 3) void attn_kernel(
    const bf16* __restrict__ q, const bf16* __restrict__ kfb,
    const bf16* __restrict__ vfb, bf16* __restrict__ o,
    float* __restrict__ pbuf)
{
    __shared__ __align__(16) bf16 Ps[4][64 * 72];   // per-wave [q][key], stride 72

    const int tid  = threadIdx.x;
    const int lane = tid & 63;
    const int wave = tid >> 6;
    const int l15  = lane & 15;
    const int l4   = lane >> 4;

    const int bh = blockIdx.x;                // fast dim -> XCD = bh % 8
    const int b  = bh >> 4, h = bh & 15;

    // dense (wt, chunk) enumeration, heavy-first; i = 0..79
    const int i = blockIdx.y * 4 + wave;
    int wt, chunk;
    if (i < 32)      { wt = 31 - (i >> 2);          chunk = i & 3; }
    else if (i < 56) { int j = i - 32; wt = 23 - j / 3;   chunk = j % 3; }
    else if (i < 72) { int j = i - 56; wt = 15 - (j >> 1); chunk = j & 1; }
    else             { wt = 7 - (i - 72);           chunk = 0; }

    const int qrow0 = wt * 64;                // wave's first q row
    const int n   = wt + 1;                   // key tiles for this q-tile
    const int nch = (wt + 8) >> 3;            // chunks of 8
    const int nt0 = chunk * 8;
    const int nt1 = (nt0 + 8 < n) ? (nt0 + 8) : n;

    bf16x8 qf[4][2];
#pragma unroll
    for (int qb = 0; qb < 4; ++qb)
#pragma unroll
        for (int kk = 0; kk < 2; ++kk)
            qf[qb][kk] = *(const bf16x8*)&q[(size_t)(b * 2048 + qrow0 + qb * 16 + l15) * 1024
                                           + h * 64 + kk * 32 + l4 * 8];

    const bf16* kb = kfb + (size_t)bh * 131072;   // 32 tiles * 4096 elems
    const bf16* vb = vfb + (size_t)bh * 131072;

    f32x4 oacc[4][4] = {};
    float lsum[4] = { 0.f, 0.f, 0.f, 0.f };

    for (int nt = nt0; nt < nt1; ++nt) {
        const bf16* kt_ = kb + nt * 4096;
        const bf16* vt_ = vb + nt * 4096;

        // K fragments -> fr (time-shared register block)
        bf16x8 fr[2][4];
#pragma unroll
        for (int kk = 0; kk < 2; ++kk)
#pragma unroll
            for (int j = 0; j < 4; ++j)
                fr[kk][j] = *(const bf16x8*)&kt_[(kk * 4 + j) * 512 + lane * 8];

        const bool diag = (nt == n - 1);
#pragma unroll
        for (int qb = 0; qb < 4; ++qb) {
            // St[key][q] = K . Q^T for this q-fragment
            f32x4 s[4] = {};
#pragma unroll
            for (int kk = 0; kk < 2; ++kk)
#pragma unroll
                for (int j = 0; j < 4; ++j)
                    s[j] = __builtin_amdgcn_mfma_f32_16x16x32_bf16(
                        fr[kk][j], qf[qb][kk], s[j], 0, 0, 0);

            // fixed-max: p = 2^s; mask only on the diagonal tile; fused cvt
            if (diag) {
                int qg = qrow0 + qb * 16 + l15;
#pragma unroll
                for (int j = 0; j < 4; ++j) {
                    int kg0 = nt * 64 + j * 16 + l4 * 4;
                    float e0 = (kg0 + 0 > qg) ? 0.f : __builtin_amdgcn_exp2f(s[j][0]);
                    float e1 = (kg0 + 1 > qg) ? 0.f : __builtin_amdgcn_exp2f(s[j][1]);
                    float e2 = (kg0 + 2 > qg) ? 0.f : __builtin_amdgcn_exp2f(s[j][2]);
                    float e3 = (kg0 + 3 > qg) ? 0.f : __builtin_amdgcn_exp2f(s[j][3]);
                    lsum[qb] += (e0 + e1) + (e2 + e3);
                    bf16x4 pk = { (bf16)e0, (bf16)e1, (bf16)e2, (bf16)e3 };
                    *(bf16x4*)&Ps[wave][(qb * 16 + l15) * 72 + j * 16 + l4 * 4] = pk;
                }
            } else {
#pragma unroll
                for (int j = 0; j < 4; ++j) {
                    float e0 = __builtin_amdgcn_exp2f(s[j][0]);
                    float e1 = __builtin_amdgcn_exp2f(s[j][1]);
                    float e2 = __builtin_amdgcn_exp2f(s[j][2]);
                    float e3 = __builtin_amdgcn_exp2f(s[j][3]);
                    lsum[qb] += (e0 + e1) + (e2 + e3);
                    bf16x4 pk = { (bf16)e0, (bf16)e1, (bf16)e2, (bf16)e3 };
                    *(bf16x4*)&Ps[wave][(qb * 16 + l15) * 72 + j * 16 + l4 * 4] = pk;
                }
            }
        }

        // V fragments reuse fr
#pragma unroll
        for (int kk = 0; kk < 2; ++kk)
#pragma unroll
            for (int j = 0; j < 4; ++j)
                fr[kk][j] = *(const bf16x8*)&vt_[(kk * 4 + j) * 512 + lane * 8];

        // O += P . V, four P-fragments per V-fragment register
#pragma unroll
        for (int kk = 0; kk < 2; ++kk) {
            bf16x8 pf[4];
#pragma unroll
            for (int qb = 0; qb < 4; ++qb)
                pf[qb] = *(const bf16x8*)&Ps[wave][(qb * 16 + l15) * 72 + kk * 32 + l4 * 8];
#pragma unroll
            for (int f = 0; f < 4; ++f)
#pragma unroll
                for (int qb = 0; qb < 4; ++qb)
                    oacc[qb][f] = __builtin_amdgcn_mfma_f32_16x16x32_bf16(
                        pf[qb], fr[kk][f], oacc[qb][f], 0, 0, 0);
        }
    }

    if (nch == 1) {
        // single chunk: normalize and store directly
#pragma unroll
        for (int qb = 0; qb < 4; ++qb) {
            float ls = lsum[qb];
            ls += __shfl_xor(ls, 16, 64);
            ls += __shfl_xor(ls, 32, 64);
            float rinv[4];
#pragma unroll
            for (int r = 0; r < 4; ++r) rinv[r] = 1.f / __shfl(ls, l4 * 4 + r, 64);
#pragma unroll
            for (int f = 0; f < 4; ++f)
#pragma unroll
                for (int r = 0; r < 4; ++r)
                    o[(size_t)(b * 2048 + qrow0 + qb * 16 + l4 * 4 + r) * 1024 + h * 64 + f * 16 + l15]
                        = (bf16)(oacc[qb][f][r] * rinv[r]);
        }
    } else {
        // partial: unnormalized O (f32, [q][d]) + per-row l at [4096..4160)
        float* ps = pbuf + ((size_t)(bh * 32 + wt) * 4 + chunk) * 4160;
#pragma unroll
        for (int qb = 0; qb < 4; ++qb) {
            float ls = lsum[qb];
            ls += __shfl_xor(ls, 16, 64);
            ls += __shfl_xor(ls, 32, 64);
            if (l4 == 0) ps[4096 + qb * 16 + l15] = ls;
#pragma unroll
            for (int f = 0; f < 4; ++f)
#pragma unroll
                for (int r = 0; r < 4; ++r)
                    ps[(qb * 16 + l4 * 4 + r) * 64 + f * 16 + l15] = oacc[qb][f][r];
        }
    }
}

// ---------------------------------------------------------------------------
// Sum <=4 partial chunks, normalize, store bf16 to ao. One block per
// (bh, wt >= 8); 256 threads: thread t owns q = t>>2, d = (t&3)*16 .. +16.
// ---------------------------------------------------------------------------
__global__ __launch_bounds__(256) void combine_kernel(
    const float* __restrict__ pbuf, bf16* __restrict__ ao)
{
    const int bh = blockIdx.x;
    const int wt = 8 + blockIdx.y;
    const int b = bh >> 4, h = bh & 15;
    const int n   = wt + 1;
    const int nch = (n + 7) >> 3;

    const int tid = threadIdx.x;
    const int qq  = tid >> 2;
    const int d0  = (tid & 3) * 16;

    const float* base0 = pbuf + (size_t)(bh * 32 + wt) * 4 * 4160;

    float ls = 0.f;
    float acc[16] = {};
    for (int c = 0; c < nch; ++c) {
        const float* p = base0 + c * 4160;
        ls += p[4096 + qq];
#pragma unroll
        for (int g = 0; g < 4; ++g) {
            float4 a = *(const float4*)(p + qq * 64 + d0 + g * 4);
            acc[g*4+0] += a.x; acc[g*4+1] += a.y; acc[g*4+2] += a.z; acc[g*4+3] += a.w;
        }
    }
    float inv = 1.f / ls;
    bf16* dst = &ao[(size_t)(b * 2048 + wt * 64 + qq) * 1024 + h * 64 + d0];
    bf16x8 r0 = { (bf16)(acc[0]*inv), (bf16)(acc[1]*inv), (bf16)(acc[2]*inv), (bf16)(acc[3]*inv),
                  (bf16)(acc[4]*inv), (bf16)(acc[5]*inv), (bf16)(acc[6]*inv), (bf16)(acc[7]*inv) };
    bf16x8 r1 = { (bf16)(acc[8]*inv), (bf16)(acc[9]*inv), (bf16)(acc[10]*inv), (bf16)(acc[11]*inv),
                  (bf16)(acc[12]*inv), (bf16)(acc[13]*inv), (bf16)(acc[14]*inv), (bf16)(acc[15]*inv) };
    *(bf16x8*)dst = r0;
    *(bf16x8*)(dst + 8) = r1;
}

// ---------------------------------------------------------------------------
extern "C" void kernel_launch(void* const* d_in, const int* in_sizes, int n_in,
                              void* d_out, int out_size, void* d_ws, size_t ws_size,
                              hipStream_t stream)
{
    const float* x  = (const float*)d_in[0];
    // d_in[1] = causal mask, implemented in-kernel
    const float* Wq = (const float*)d_in[2];
    const float* bq = (const float*)d_in[3];
    const float* Wk = (const float*)d_in[4];
    const float* Wv = (const float*)d_in[5];
    const float* bv = (const float*)d_in[6];
    const float* Wo = (const float*)d_in[7];
    const float* bo = (const float*)d_in[8];
    float* out = (float*)d_out;

    const size_t M1 = 1024ull * 1024ull, M4 = 4ull * M1;
    bf16* base = (bf16*)d_ws;
    bf16* xb  = base;              // 4M; dead after qkv -> ao aliases it
    bf16* wqb = base + M4;
    bf16* wkb = base + M4 + M1;
    bf16* wvb = base + M4 + 2 * M1;
    bf16* wob = base + M4 + 3 * M1;
    bf16* q   = base + 8 * M1;
    bf16* kfb = base + 12 * M1;    // K fragment-major
    bf16* vfb = base + 16 * M1;    // V fragment-major
    bf16* ao  = xb;
    float* pbuf = (float*)(base + 20 * M1);   // 1024 tiles * 4 chunks * 4160 f32 = 68 MB

    convert_kernel<<<4096, 256, 0, stream>>>(x, Wq, Wk, Wv, Wo, base);
    qkv_kernel<<<dim3(32, 24), 256, 0, stream>>>(xb, wqb, bq, wkb, wvb, bv, q, kfb, vfb);
    attn_kernel<<<dim3(32, 20), 256, 0, stream>>>(q, kfb, vfb, ao, pbuf);
    combine_kernel<<<dim3(32, 24), 256, 0, stream>>>(pbuf, ao);
    oproj_kernel<<<dim3(32, 8), 256, 0, stream>>>(ao, wob, bo, out);
}